// Round 2
// baseline (872.215 us; speedup 1.0000x reference)
//
#include <hip/hip_runtime.h>

// deltaLayer: out[b,c,i,j] = |l[b,c,j] - r[b,c,i]|
// BS=2, CHAN=128, H=1, W=900 -> out is (2,128,900,900) fp32 = 829.4 MB.
// Pure write-BW bound: stage tiny l/r rows in LDS, stream coalesced
// nontemporal float4 stores.

#define BS    2
#define CHAN  128
#define W     900
#define W4    225                // W/4 float4 per output row
#define TILE4 (W * W4)           // 202500 float4 per (b,c) tile
#define SPLIT 4                  // blocks per (b,c) tile
#define PART  (TILE4 / SPLIT)    // 50625 float4 per block

typedef float v4f __attribute__((ext_vector_type(4)));

__global__ __launch_bounds__(256, 4)
void deltaLayer_57294863728910_kernel(const float* __restrict__ l,
                                      const float* __restrict__ r,
                                      float* __restrict__ out) {
    __shared__ float sl[W];
    __shared__ float sr[W];

    const int bc   = blockIdx.x >> 2;   // (b*CHAN + c), 0..255
    const int part = blockIdx.x & (SPLIT - 1);

    const float* lrow = l + bc * W;
    const float* rrow = r + bc * W;
    for (int t = threadIdx.x; t < W; t += 256) {
        sl[t] = lrow[t];
        sr[t] = rrow[t];
    }
    __syncthreads();

    v4f* out4 = (v4f*)out + (size_t)bc * TILE4;

    const int kbeg = part * PART + threadIdx.x;
    const int kend = (part + 1) * PART;
    for (int k = kbeg; k < kend; k += 256) {
        int i  = k / W4;                 // magic-multiply, no HW div
        int j4 = k - i * W4;
        float rv = sr[i];
        v4f   lv = *(const v4f*)&sl[j4 * 4];
        v4f   o;
        o.x = fabsf(lv.x - rv);
        o.y = fabsf(lv.y - rv);
        o.z = fabsf(lv.z - rv);
        o.w = fabsf(lv.w - rv);
        __builtin_nontemporal_store(o, &out4[k]);
    }
}

extern "C" void kernel_launch(void* const* d_in, const int* in_sizes, int n_in,
                              void* d_out, int out_size, void* d_ws, size_t ws_size,
                              hipStream_t stream) {
    const float* l = (const float*)d_in[0];
    const float* r = (const float*)d_in[1];
    float* out = (float*)d_out;

    dim3 grid(BS * CHAN * SPLIT);   // 1024 blocks
    dim3 block(256);
    deltaLayer_57294863728910_kernel<<<grid, block, 0, stream>>>(l, r, out);
}